// Round 4
// baseline (421.233 us; speedup 1.0000x reference)
//
#include <hip/hip_runtime.h>

#define NB 32
#define NR 16384
#define NF 256
#define NH 16
#define TOT (NB*NR)
#define RPB 256      // rows per block in k_scores
#define KC 32        // K-chunk
#define LSTR 33      // LDS row stride: bank=(t+k)%32 on reads -> 2-way (free)

typedef unsigned long long u64;

__device__ __forceinline__ unsigned int f2u(float f) {
    unsigned int u = __float_as_uint(f);
    return (u & 0x80000000u) ? ~u : (u | 0x80000000u);
}
__device__ __forceinline__ float u2f(unsigned int s) {
    unsigned int u = (s & 0x80000000u) ? (s ^ 0x80000000u) : ~s;
    return __uint_as_float(u);
}

// ---------------- Kernel 0: fold constants --------------------------------
__global__ __launch_bounds__(256) void k_prep(
    const float* __restrict__ ln1_g, const float* __restrict__ ln1_b,
    const float* __restrict__ W1, const float* __restrict__ b1,
    const float* __restrict__ ln2_g, const float* __restrict__ ln2_b,
    const float* __restrict__ W2, const float* __restrict__ b2,
    float* __restrict__ W1g, float* __restrict__ consts)
{
    __shared__ float redc[16][16];
    __shared__ float redu[16][16];
    const int t = threadIdx.x;
    for (int e = t; e < NF*NH; e += 256) {
        int k = e >> 4;
        W1g[e] = ln1_g[k] * W1[e];
    }
    const int h = t & 15, kp = t >> 4;
    float pc = 0.f, pu = 0.f;
    #pragma unroll
    for (int r = 0; r < 16; ++r) {
        int k = kp*16 + r;
        float w = W1[k*NH + h];
        pc += ln1_b[k] * w;
        pu += ln1_g[k] * w;
    }
    redc[kp][h] = pc; redu[kp][h] = pu;
    __syncthreads();
    if (t < 16) {
        float sc = 0.f, su = 0.f;
        #pragma unroll
        for (int r = 0; r < 16; ++r) { sc += redc[r][t]; su += redu[r][t]; }
        consts[t]      = sc + b1[t];
        consts[16 + t] = su;
        consts[32 + t] = ln2_g[t] * W2[t];
    }
    if (t == 0) {
        float U2 = 0.f, C2 = b2[0];
        for (int hh = 0; hh < 16; ++hh) {
            U2 += ln2_g[hh] * W2[hh];
            C2 += ln2_b[hh] * W2[hh];
        }
        consts[48] = U2;
        consts[49] = C2;
    }
}

// ---------------- Kernel 1: thread-per-row fused scores -------------------
__global__ __launch_bounds__(256) void k_scores(
    const float* __restrict__ table,
    const float* __restrict__ W1g,
    const float* __restrict__ consts,
    u64* __restrict__ keys)
{
    __shared__ float xt[RPB * LSTR];   // 33,792 B -> 4 blocks/CU
    const int t = threadIdx.x;
    const size_t rowBase = (size_t)blockIdx.x * RPB;

    float dx[16];
    #pragma unroll
    for (int h = 0; h < 16; ++h) dx[h] = 0.f;
    float sum = 0.f, ssq = 0.f;

    for (int c = 0; c < NF/KC; ++c) {
        float4 v[8];
        #pragma unroll
        for (int p = 0; p < 8; ++p) {
            int q = p*256 + t;
            int r = q >> 3, cg = q & 7;
            v[p] = *(const float4*)(table + (rowBase + r)*NF + c*KC + cg*4);
        }
        __syncthreads();   // previous chunk's xt reads complete
        #pragma unroll
        for (int p = 0; p < 8; ++p) {
            int q = p*256 + t;
            int r = q >> 3, cg = q & 7;
            float* dst = xt + r*LSTR + cg*4;
            dst[0] = v[p].x; dst[1] = v[p].y; dst[2] = v[p].z; dst[3] = v[p].w;
        }
        __syncthreads();

        const float4* __restrict__ Wg4 = (const float4*)W1g + (size_t)c*KC*4;
        const float*  __restrict__ xr  = xt + t*LSTR;
        #pragma unroll 4
        for (int k = 0; k < KC; ++k) {
            float x = xr[k];
            float4 w0 = Wg4[k*4+0];
            float4 w1 = Wg4[k*4+1];
            float4 w2 = Wg4[k*4+2];
            float4 w3 = Wg4[k*4+3];
            sum += x;
            ssq = fmaf(x, x, ssq);
            dx[ 0] = fmaf(x, w0.x, dx[ 0]);
            dx[ 1] = fmaf(x, w0.y, dx[ 1]);
            dx[ 2] = fmaf(x, w0.z, dx[ 2]);
            dx[ 3] = fmaf(x, w0.w, dx[ 3]);
            dx[ 4] = fmaf(x, w1.x, dx[ 4]);
            dx[ 5] = fmaf(x, w1.y, dx[ 5]);
            dx[ 6] = fmaf(x, w1.z, dx[ 6]);
            dx[ 7] = fmaf(x, w1.w, dx[ 7]);
            dx[ 8] = fmaf(x, w2.x, dx[ 8]);
            dx[ 9] = fmaf(x, w2.y, dx[ 9]);
            dx[10] = fmaf(x, w2.z, dx[10]);
            dx[11] = fmaf(x, w2.w, dx[11]);
            dx[12] = fmaf(x, w3.x, dx[12]);
            dx[13] = fmaf(x, w3.y, dx[13]);
            dx[14] = fmaf(x, w3.z, dx[14]);
            dx[15] = fmaf(x, w3.w, dx[15]);
        }
    }

    const float mu   = sum * (1.f/NF);
    const float var  = ssq * (1.f/NF) - mu*mu;
    const float rstd = rsqrtf(var + 1e-5f);
    float s2 = 0.f, q2 = 0.f, dh = 0.f;
    #pragma unroll
    for (int h = 0; h < 16; ++h) {
        float hv = rstd * (dx[h] - mu * consts[16 + h]) + consts[h];
        hv = fmaxf(hv, 0.f);
        s2 += hv;
        q2 = fmaf(hv, hv, q2);
        dh = fmaf(hv, consts[32 + h], dh);
    }
    const float mu2   = s2 * (1.f/NH);
    const float var2  = q2 * (1.f/NH) - mu2*mu2;
    const float rstd2 = rsqrtf(var2 + 1e-5f);
    const float sc    = rstd2 * (dh - mu2 * consts[48]) + consts[49];

    const size_t row = rowBase + t;
    keys[row] = ((u64)f2u(sc) << 32) | (u64)(row & (NR-1));
}

// ---------------- Kernel 2: bitonic sort, 2048-chunks + register passes ---
__global__ __launch_bounds__(1024) void k_sort_local_first(u64* __restrict__ keys) {
    __shared__ u64 sk[2048];
    const int base_g = blockIdx.x * 2048;
    sk[threadIdx.x]        = keys[base_g + threadIdx.x];
    sk[threadIdx.x + 1024] = keys[base_g + threadIdx.x + 1024];
    __syncthreads();
    for (int k = 2; k <= 2048; k <<= 1) {
        for (int j = k >> 1; j > 0; j >>= 1) {
            int t = threadIdx.x;
            int i = ((t & ~(j-1)) << 1) | (t & (j-1));
            int l = i | j;
            int gi = (base_g + i) & (NR - 1);
            bool dir = ((gi & k) == 0);
            u64 a = sk[i], b = sk[l];
            if ((b > a) == dir) { sk[i] = b; sk[l] = a; }
            __syncthreads();
        }
    }
    keys[base_g + threadIdx.x]        = sk[threadIdx.x];
    keys[base_g + threadIdx.x + 1024] = sk[threadIdx.x + 1024];
}

// cross-chunk phases j>=2048 for merge step k: all in registers.
// thread owns elements i = c + g*2048 (g=0..7) of one batch.
__global__ __launch_bounds__(256) void k_merge_high(u64* __restrict__ keys, int k) {
    const int gt = blockIdx.x * 256 + threadIdx.x;
    const int b  = gt >> 11;
    const int c  = gt & 2047;
    u64* kb = keys + (size_t)b * NR + c;
    u64 e[8];
    #pragma unroll
    for (int g = 0; g < 8; ++g) e[g] = kb[g * 2048];
    const int kg = k >> 11;   // 2, 4, or 8
    for (int jg = kg >> 1; jg >= 1; jg >>= 1) {
        #pragma unroll
        for (int g = 0; g < 8; ++g) {
            if (!(g & jg)) {
                int l = g | jg;
                bool dir = ((g & kg) == 0);
                u64 a = e[g], d = e[l];
                if ((d > a) == dir) { e[g] = d; e[l] = a; }
            }
        }
    }
    #pragma unroll
    for (int g = 0; g < 8; ++g) kb[g * 2048] = e[g];
}

// within-chunk phases j<=1024 for merge step K (K>=4096: dir uniform/chunk)
__global__ __launch_bounds__(1024) void k_sort_local_merge(u64* __restrict__ keys, int K) {
    __shared__ u64 sk[2048];
    const int base_g = blockIdx.x * 2048;
    const bool dir = (((base_g & (NR-1)) & K) == 0);
    sk[threadIdx.x]        = keys[base_g + threadIdx.x];
    sk[threadIdx.x + 1024] = keys[base_g + threadIdx.x + 1024];
    __syncthreads();
    for (int j = 1024; j > 0; j >>= 1) {
        int t = threadIdx.x;
        int i = ((t & ~(j-1)) << 1) | (t & (j-1));
        int l = i | j;
        u64 a = sk[i], b = sk[l];
        if ((b > a) == dir) { sk[i] = b; sk[l] = a; }
        __syncthreads();
    }
    keys[base_g + threadIdx.x]        = sk[threadIdx.x];
    keys[base_g + threadIdx.x + 1024] = sk[threadIdx.x + 1024];
}

// ---------------- Kernel 3: isotonic via LCM of cumsum, all-LDS -----------
__global__ __launch_bounds__(1024) void k_pava(
    const u64* __restrict__ keys, const int* __restrict__ capp,
    float* __restrict__ out_soft, float* __restrict__ out_bins)
{
    __shared__ float  Sf[NR];      // 64 KiB residual (within-thread scan)
    __shared__ double Cd[1024];    // 8 KiB exclusive block prefix (f64)
    __shared__ double Wt[16];      // wave totals
    __shared__ int    H[NR + 1];   // 64 KiB hull stack
    __shared__ int    cnt[1024];
    __shared__ int    ti[512], tj[512], crA[512];

    const int b = blockIdx.x;
    const int tid = threadIdx.x;
    const int lane = tid & 63;
    const int wid = tid >> 6;
    const u64* kb = keys + (size_t)b*NR;

    const float mx = u2f((unsigned)(kb[0] >> 32));
    const float mn = u2f((unsigned)(kb[NR-1] >> 32));
    const float scale = 10000.0f / (mx - mn);

    // 1) per-thread 16-element local scan of y = s_scaled - w (f64)
    double loc[16];
    double acc = 0.0;
    const int base = tid * 16;
    #pragma unroll
    for (int r = 0; r < 16; ++r) {
        int i = base + r;
        u64 key = kb[i];
        float s_i = (u2f((unsigned)(key >> 32)) - mn) * scale;
        double y = (double)s_i - (double)(NR - i);
        acc += y;
        loc[r] = acc;
        Sf[i] = (float)acc;          // |acc| <= 2.7e5 -> abs err ~0.016
    }
    // 2) block-exclusive prefix of per-thread totals (shuffle scan, f64)
    double v = acc;
    #pragma unroll
    for (int d = 1; d < 64; d <<= 1) {
        double o = __shfl_up(v, d, 64);
        if (lane >= d) v += o;
    }
    if (lane == 63) Wt[wid] = v;
    __syncthreads();
    if (tid < 16) {
        double w = Wt[tid];
        #pragma unroll
        for (int d = 1; d < 16; d <<= 1) {
            double o = __shfl_up(w, d, 16);
            if ((tid & 15) >= d) w += o;
        }
        Wt[tid] = w;
    }
    __syncthreads();
    const double wbase = (wid == 0) ? 0.0 : Wt[wid - 1];
    Cd[tid] = wbase + (v - acc);     // exclusive prefix for this thread-block
    __syncthreads();

    // S value at diagram point k (cumsum through element k-1); S(0)=0
    #define SVP(i) (Cd[(i) >> 4] + (double)Sf[i])
    #define SVAL(k) ((k) == 0 ? 0.0 : SVP((k)-1))
    #define CRS(ka, kb_, kc) ( (double)((kb_)-(ka)) * (SVAL(kc) - SVAL(ka)) \
                             - (SVAL(kb_) - SVAL(ka)) * (double)((kc)-(ka)) )

    // 3) level-0: 16-point chunk upper hulls
    {
        int out = 0;
        #pragma unroll 1
        for (int r = 0; r < 16; ++r) {
            int k = base + r;
            while (out >= 2) {
                int kb2 = H[base + out - 1], ka = H[base + out - 2];
                if (CRS(ka, kb2, k) >= 0.0) --out;
                else break;
            }
            H[base + out++] = k;
        }
        cnt[tid] = out;
    }

    // 4) pairwise merges via upper tangent + parallel suffix copy
    for (int lev = 0; lev < 10; ++lev) {
        __syncthreads();
        const int pairs = 512 >> lev;
        const int Wd = 16 << lev;
        if (tid < pairs) {
            const int lbase = tid * 2 * Wd;
            const int rbase = lbase + Wd;
            int cl = cnt[(2*tid) << lev];
            int cr = cnt[(2*tid+1) << lev];
            int i = cl - 1, j = 0;
            bool moved = true;
            while (moved) {
                moved = false;
                while (i > 0) {
                    int ka = H[lbase+i-1], kb2 = H[lbase+i], kc = H[rbase+j];
                    if (CRS(ka, kb2, kc) >= 0.0) { --i; moved = true; }
                    else break;
                }
                while (j < cr - 1) {
                    int ka = H[lbase+i], kb2 = H[rbase+j], kc = H[rbase+j+1];
                    if (CRS(ka, kb2, kc) >= 0.0) { ++j; moved = true; }
                    else break;
                }
            }
            ti[tid] = i; tj[tid] = j; crA[tid] = cr;
            cnt[(2*tid) << lev] = (i + 1) + (cr - j);
        }
        __syncthreads();
        const int tpp = 2 << lev;
        const int p = tid >> (1 + lev);
        const int q = tid & (tpp - 1);
        int vals[8];
        int len = 0, srcb = 0, dstb = 0;
        if (p < pairs) {
            const int lbase = p * 2 * Wd;
            const int rbase = lbase + Wd;
            const int i = ti[p], j = tj[p], cr = crA[p];
            len = cr - j;
            srcb = rbase + j;
            dstb = lbase + i + 1;
            #pragma unroll
            for (int t = 0; t < 8; ++t) {
                int e = q + t * tpp;
                if (e < len) vals[t] = H[srcb + e];
            }
        }
        __syncthreads();
        if (p < pairs) {
            #pragma unroll
            for (int t = 0; t < 8; ++t) {
                int e = q + t * tpp;
                if (e < len) H[dstb + e] = vals[t];
            }
        }
        __syncthreads();
    }

    // 5) append rightmost point k = NR
    if (tid == 0) {
        int out = cnt[0];
        while (out >= 2) {
            int kb2 = H[out - 1], ka = H[out - 2];
            if (CRS(ka, kb2, NR) >= 0.0) --out;
            else break;
        }
        H[out++] = NR;
        cnt[0] = out;
    }
    __syncthreads();

    // 6) slopes -> dual -> primal; scatter; bins from hard rank
    const int m = cnt[0];
    const int cap = capp[0];
    for (int i = tid; i < NR; i += 1024) {
        int lo = 0, hi = m - 1;
        while (hi - lo > 1) {
            int mid = (lo + hi) >> 1;
            if (H[mid] <= i) lo = mid; else hi = mid;
        }
        int ka = H[lo], kb2 = H[hi];
        double slope = (SVAL(kb2) - SVAL(ka)) / (double)(kb2 - ka);
        u64 key = kb[i];
        float s_i = (u2f((unsigned)(key >> 32)) - mn) * scale;
        float primal = (float)((double)s_i - slope);
        int idx = (int)(key & 0xffffffffu);
        out_soft[(size_t)b*NR + idx] = primal;
        int rank = (NR - 1) - i;
        out_bins[(size_t)b*NR + idx] = (float)(rank / cap + 1);
    }
    #undef SVP
    #undef SVAL
    #undef CRS
}

extern "C" void kernel_launch(void* const* d_in, const int* in_sizes, int n_in,
                              void* d_out, int out_size, void* d_ws, size_t ws_size,
                              hipStream_t stream)
{
    const float* table = (const float*)d_in[0];
    const float* ln1_g = (const float*)d_in[1];
    const float* ln1_b = (const float*)d_in[2];
    const float* W1    = (const float*)d_in[3];
    const float* b1    = (const float*)d_in[4];
    const float* ln2_g = (const float*)d_in[5];
    const float* ln2_b = (const float*)d_in[6];
    const float* W2    = (const float*)d_in[7];
    const float* b2    = (const float*)d_in[8];
    const int*   cap   = (const int*)d_in[9];

    u64*   keys   = (u64*)d_ws;                  // TOT u64 (4 MiB)
    float* W1g    = (float*)(keys + TOT);        // 4096 f32
    float* consts = W1g + NF*NH;                 // 64 f32

    float* out_soft = (float*)d_out;
    float* out_bins = ((float*)d_out) + TOT;

    k_prep<<<1, 256, 0, stream>>>(ln1_g, ln1_b, W1, b1, ln2_g, ln2_b, W2, b2,
                                  W1g, consts);
    k_scores<<<TOT/RPB, 256, 0, stream>>>(table, W1g, consts, keys);

    k_sort_local_first<<<TOT/2048, 1024, 0, stream>>>(keys);
    k_merge_high<<<TOT/2048, 256, 0, stream>>>(keys, 4096);
    k_sort_local_merge<<<TOT/2048, 1024, 0, stream>>>(keys, 4096);
    k_merge_high<<<TOT/2048, 256, 0, stream>>>(keys, 8192);
    k_sort_local_merge<<<TOT/2048, 1024, 0, stream>>>(keys, 8192);
    k_merge_high<<<TOT/2048, 256, 0, stream>>>(keys, 16384);
    k_sort_local_merge<<<TOT/2048, 1024, 0, stream>>>(keys, 16384);

    k_pava<<<NB, 1024, 0, stream>>>(keys, cap, out_soft, out_bins);
}